// Round 4
// baseline (863.475 us; speedup 1.0000x reference)
//
#include <hip/hip_runtime.h>

typedef unsigned int uint32;
typedef unsigned short ushort16;

typedef __attribute__((ext_vector_type(8))) short bf16x8;
typedef __attribute__((ext_vector_type(4))) float f32x4;

#define NNODES 32768
#define DFEAT 384
#define KPAD1 320

__device__ __forceinline__ float bf2f(ushort16 u) {
  union { uint32 i; float f; } x; x.i = ((uint32)u) << 16; return x.f;
}
__device__ __forceinline__ float bflo(uint32 v) {
  union { uint32 i; float f; } x; x.i = v << 16; return x.f;
}
__device__ __forceinline__ float bfhi(uint32 v) {
  union { uint32 i; float f; } x; x.i = v & 0xffff0000u; return x.f;
}
__device__ __forceinline__ ushort16 f2bf(float f) {
  union { float f; uint32 i; } x; x.f = f;
  uint32 r = (x.i + 0x7fffu + ((x.i >> 16) & 1u)) >> 16;
  return (ushort16)r;
}
__device__ __forceinline__ uint32 pack2(float a, float b) {
  return (uint32)f2bf(a) | ((uint32)f2bf(b) << 16);
}

// ---------------- fused prep: convert_x + deg_count + sent_mean ------------
// blocks [0,4096): convert x_nodes f32 [32768,300] -> bf16 [32768,320], float4
// blocks [4096, 4096+degB): deg_count atomics
// blocks [4096+degB, +1024): sent_mean partials, float4, per-wave (64 partials)
__global__ __launch_bounds__(256) void prep_kernel(
    const float* __restrict__ X, ushort16* __restrict__ A0,
    const int* __restrict__ dst, int* __restrict__ cnt, int E, int degB,
    const float* __restrict__ last, const float* __restrict__ first,
    float* __restrict__ Hpart) {
  int bx = blockIdx.x;
  int tid = threadIdx.x;
  if (bx < 4096) {
    int r = tid >> 5, lane = tid & 31;
    int row = bx * 8 + r;
    const f32x4* xr = (const f32x4*)(X + (size_t)row * 300);  // 75 float4/row
    uint2* ar = (uint2*)(A0 + (size_t)row * KPAD1);           // 80 uint2/row
#pragma unroll
    for (int i = 0; i < 3; ++i) {
      int c = lane + i * 32;
      if (c < 75) {
        f32x4 v = xr[c];
        uint2 o; o.x = pack2(v.x, v.y); o.y = pack2(v.z, v.w);
        ar[c] = o;
      } else if (c < 80) {
        uint2 z; z.x = 0u; z.y = 0u;
        ar[c] = z;
      }
    }
  } else if (bx < 4096 + degB) {
    int e = (bx - 4096) * 256 + tid;
    if (e < E) atomicAdd(&cnt[dst[e]], 1);
  } else {
    int idx = bx - 4096 - degB;        // [0,1024): b + 64*sc
    int b = idx & 63, sc = idx >> 6;
    int w = tid >> 6, lane = tid & 63;
    const f32x4* L = (const f32x4*)last;   // 192 float4 per row
    const f32x4* F = (const f32x4*)first;
    f32x4 a0 = (f32x4)0.f, a1 = (f32x4)0.f, a2 = (f32x4)0.f;
    size_t rowbase = ((size_t)b * 512 + sc * 32 + w) * 192;
#pragma unroll
    for (int i = 0; i < 8; ++i) {
      size_t rb = rowbase + (size_t)(4 * 192) * i;
      f32x4 l0 = L[rb + lane],       f0 = F[rb + lane];
      f32x4 l1 = L[rb + lane + 64],  f1 = F[rb + lane + 64];
      f32x4 l2 = L[rb + lane + 128], f2 = F[rb + lane + 128];
      a0 += l0 + f0; a1 += l1 + f1; a2 += l2 + f2;
    }
    f32x4* HP = (f32x4*)Hpart;
    size_t p = ((size_t)(sc * 4 + w) * 64 + b) * 192;
    HP[p + lane] = a0; HP[p + lane + 64] = a1; HP[p + lane + 128] = a2;
  }
}

// ---------------- scan (+ disq folded), int4 reads --------------------------
__global__ void scan_kernel(const int* __restrict__ cnt, int* __restrict__ row_start,
                            int* __restrict__ cursor, float* __restrict__ disq) {
  __shared__ int buf[1024];
  int t = threadIdx.x;
  int base = t * 32;
  const int4* c4 = (const int4*)cnt;
  int4 loc[8];
  int s = 0;
#pragma unroll
  for (int i = 0; i < 8; ++i) {
    loc[i] = c4[t * 8 + i];
    s += loc[i].x + loc[i].y + loc[i].z + loc[i].w;
  }
  buf[t] = s; __syncthreads();
  int x = s;
  for (int off = 1; off < 1024; off <<= 1) {
    int v = (t >= off) ? buf[t - off] : 0;
    __syncthreads();
    x += v; buf[t] = x;
    __syncthreads();
  }
  int run = x - s;
#pragma unroll
  for (int i = 0; i < 8; ++i) {
    int4 v = loc[i];
    int j = base + i * 4;
    row_start[j + 0] = run; cursor[j + 0] = run; disq[j + 0] = rsqrtf((float)v.x + 1.0f); run += v.x;
    row_start[j + 1] = run; cursor[j + 1] = run; disq[j + 1] = rsqrtf((float)v.y + 1.0f); run += v.y;
    row_start[j + 2] = run; cursor[j + 2] = run; disq[j + 2] = rsqrtf((float)v.z + 1.0f); run += v.z;
    row_start[j + 3] = run; cursor[j + 3] = run; disq[j + 3] = rsqrtf((float)v.w + 1.0f); run += v.w;
  }
  if (t == 1023) row_start[NNODES] = run;
}

// ---------------- scatter (+ hsent fold, float4) ----------------------------
__global__ __launch_bounds__(256) void scatter_kernel(
    const int* __restrict__ src, const int* __restrict__ dst,
    int* __restrict__ cursor, int* __restrict__ csr, int E, int degB,
    const float* __restrict__ Hpart, float* __restrict__ Hsent) {
  int bx = blockIdx.x, t = threadIdx.x;
  if (bx < degB) {
    int e = bx * 256 + t;
    if (e < E) {
      int d = dst[e];
      int pos = atomicAdd(&cursor[d], 1);
      csr[pos] = src[e];
    }
  } else {
    int b = bx - degB;                 // [0,64)
    if (t < 192) {
      const f32x4* HP = (const f32x4*)Hpart;
      f32x4 h = (f32x4)0.f;
#pragma unroll 4
      for (int p = 0; p < 64; ++p)
        h += HP[((size_t)p * 64 + b) * 192 + t];
      ((f32x4*)Hsent)[(size_t)b * 192 + t] = h * (0.5f / 512.f);
    }
  }
}

// ---------------- weight transform with inline BN-affine from spread stats --
__global__ void xform_w_kernel(const float* __restrict__ W, const float* __restrict__ bias,
                               const float* __restrict__ stat, const float* __restrict__ g,
                               const float* __restrict__ bb, float invN,
                               ushort16* __restrict__ BT, float* __restrict__ bias_out,
                               int K, int Kpad, int Nw) {
  __shared__ float red[128];
  int n = blockIdx.x, t = threadIdx.x;
  float part = 0.f;
  for (int k = t; k < Kpad; k += 128) {
    ushort16 o = 0; float contrib = 0.f;
    if (k < K) {
      float ak = 1.f, shk = 0.f;
      if (stat) {
        float s = 0.f, q = 0.f;
        for (int i = 0; i < 8; ++i) { s += stat[k * 8 + i]; q += stat[(DFEAT + k) * 8 + i]; }
        float mean = s * invN, var = q * invN - mean * mean;
        ak = g[k] * rsqrtf(var + 1e-5f);
        shk = bb[k] - ak * mean;
      }
      float w = W[(size_t)k * Nw + n];
      o = f2bf(ak * w);
      contrib = shk * w;
    }
    BT[(size_t)n * Kpad + k] = o;
    part += contrib;
  }
  red[t] = part; __syncthreads();
  for (int off = 64; off > 0; off >>= 1) {
    if (t < off) red[t] += red[t + off];
    __syncthreads();
  }
  if (t == 0) bias_out[n] = (bias ? bias[n] : 0.f) + red[0];
}

// ---------------- MFMA bf16 GEMM with fused stats / row-scale ---------------
#define BM 128
#define BN 128
#define BKT 32
#define LDT 40  // BKT + 8 pad shorts

template <bool RELU, bool STATS, bool RSCALE>
__global__ __launch_bounds__(256) void gemm_bf16(
    const ushort16* __restrict__ A, int lda, const ushort16* __restrict__ BT, int ldb,
    const float* __restrict__ bias, const float* __restrict__ rowscale,
    ushort16* __restrict__ C, int Ntot, int K, float* __restrict__ stat) {
  __shared__ __attribute__((aligned(16))) ushort16 As[BM * LDT];
  __shared__ __attribute__((aligned(16))) ushort16 Bs[BN * LDT];
  __shared__ float ssum[BN], ssq[BN];
  int bm0 = blockIdx.x * BM, bn0 = blockIdx.y * BN;
  int tid = threadIdx.x;
  if (STATS) {
    if (tid < BN) { ssum[tid] = 0.f; ssq[tid] = 0.f; }
  }
  int lane = tid & 63, wave = tid >> 6;
  int wm = (wave & 1) * 64, wn = (wave >> 1) * 64;
  int l15 = lane & 15, quad = lane >> 4;

  f32x4 acc[4][4];
  for (int i = 0; i < 4; ++i)
    for (int j = 0; j < 4; ++j) acc[i][j] = (f32x4)0.f;

  for (int kk = 0; kk < K; kk += BKT) {
    __syncthreads();
    for (int i = 0; i < 2; ++i) {
      int chunk = tid + i * 256;
      int row = chunk >> 2, cc = chunk & 3;
      uint4 va = *(const uint4*)(A + (size_t)(bm0 + row) * lda + kk + cc * 8);
      *(uint4*)(&As[row * LDT + cc * 8]) = va;
      uint4 vb = *(const uint4*)(BT + (size_t)(bn0 + row) * ldb + kk + cc * 8);
      *(uint4*)(&Bs[row * LDT + cc * 8]) = vb;
    }
    __syncthreads();
    bf16x8 af[4], bfr[4];
    for (int mi = 0; mi < 4; ++mi)
      af[mi] = *(const bf16x8*)(&As[(wm + mi * 16 + l15) * LDT + quad * 8]);
    for (int ni = 0; ni < 4; ++ni)
      bfr[ni] = *(const bf16x8*)(&Bs[(wn + ni * 16 + l15) * LDT + quad * 8]);
    for (int mi = 0; mi < 4; ++mi)
      for (int ni = 0; ni < 4; ++ni)
        acc[mi][ni] = __builtin_amdgcn_mfma_f32_16x16x32_bf16(af[mi], bfr[ni], acc[mi][ni], 0, 0, 0);
  }
  for (int ni = 0; ni < 4; ++ni) {
    int coll = wn + ni * 16 + l15;
    int col = bn0 + coll;
    float bv = bias[col];
    float s = 0.f, q = 0.f;
    for (int mi = 0; mi < 4; ++mi) {
      for (int r = 0; r < 4; ++r) {
        int row = bm0 + wm + mi * 16 + quad * 4 + r;
        float v = acc[mi][ni][r] + bv;
        if (RELU) v = fmaxf(v, 0.f);
        if (RSCALE) v *= rowscale[row];
        C[(size_t)row * Ntot + col] = f2bf(v);
        if (STATS) { s += v; q += v * v; }
      }
    }
    if (STATS) { atomicAdd(&ssum[coll], s); atomicAdd(&ssq[coll], q); }
  }
  if (STATS) {
    __syncthreads();
    int sp = blockIdx.x & 7;
    if (tid < BN) {
      atomicAdd(&stat[(bn0 + tid) * 8 + sp], ssum[tid]);
      atomicAdd(&stat[(DFEAT + bn0 + tid) * 8 + sp], ssq[tid]);
    }
  }
}

// ---------------- balanced XCD-affine GCN aggregation -----------------------
// Proven r1 inner loop (32-lane uint32 gather) + balanced unit mapping:
// 6 chunks x 1024 groups = 6144 units; XCD k (bx&7) owns units [768k,768k+768)
__global__ void __launch_bounds__(256) aggregate_kernel(
    const uint32* __restrict__ XWs, const int* __restrict__ csr,
    const int* __restrict__ row_start, const float* __restrict__ disq,
    const float* __restrict__ bconv, uint32* __restrict__ RC2,
    float* __restrict__ stat) {
  int bx = blockIdx.x;                 // grid 6144
  int unit = (bx & 7) * 768 + (bx >> 3);
  int chunk = unit >> 10;              // [0,6)
  int g = unit & 1023;                 // [0,1024)
  __shared__ float ssum[64], ssq[64];
  int tid = threadIdx.x;
  if (tid < 64) { ssum[tid] = 0.f; ssq[tid] = 0.f; }
  __syncthreads();
  int lane = tid & 63, wave = tid >> 6;
  int half = lane >> 5, cl = lane & 31;
  int hb = half << 5;
  int cbase = chunk * 32;
  float b0 = bconv[chunk * 64 + 2 * cl], b1 = bconv[chunk * 64 + 2 * cl + 1];
  float ls0 = 0.f, ls1 = 0.f, lq0 = 0.f, lq1 = 0.f;
  int nodebase = (g * 4 + wave) * 8;
  for (int ni = 0; ni < 8; ++ni) {
    int n = nodebase + ni;
    int beg = row_start[n], end = row_start[n + 1];
    int deg = end - beg;
    int len0 = (deg + 1) >> 1;  // half 0 gets the longer part
    int myBeg = beg + (half ? len0 : 0);
    int myLen = half ? (deg - len0) : len0;
    float a0, a1;
    if (half == 0) {
      uint32 v = XWs[(size_t)n * 192 + cbase + cl];
      a0 = bflo(v); a1 = bfhi(v);
    } else { a0 = 0.f; a1 = 0.f; }
    for (int bb0 = 0; bb0 < len0; bb0 += 32) {
      int rem = myLen - bb0;
      int idx = (cl < rem) ? csr[myBeg + bb0 + cl] : -1;
      int jmax = min(32, len0 - bb0);  // uniform over wave
      int j = 0;
      for (; j + 8 <= jmax; j += 8) {
        uint32 v[8];
#pragma unroll
        for (int jj = 0; jj < 8; ++jj) {
          int s = __shfl(idx, hb + j + jj, 64);
          int sa = (s < 0) ? 0 : s;                 // safe address
          uint32 m = (s < 0) ? 0u : 0xffffffffu;    // zero-mask invalid
          v[jj] = XWs[(size_t)sa * 192 + cbase + cl] & m;
        }
#pragma unroll
        for (int jj = 0; jj < 8; ++jj) { a0 += bflo(v[jj]); a1 += bfhi(v[jj]); }
      }
      for (; j < jmax; ++j) {
        int s = __shfl(idx, hb + j, 64);
        int sa = (s < 0) ? 0 : s;
        uint32 m = (s < 0) ? 0u : 0xffffffffu;
        uint32 v = XWs[(size_t)sa * 192 + cbase + cl] & m;
        a0 += bflo(v); a1 += bfhi(v);
      }
    }
    a0 += __shfl_xor(a0, 32, 64);
    a1 += __shfl_xor(a1, 32, 64);
    if (half == 0) {
      float din = disq[n];
      a0 = fmaxf(din * a0 + b0, 0.f);
      a1 = fmaxf(din * a1 + b1, 0.f);
      RC2[(size_t)n * 192 + cbase + cl] = (uint32)f2bf(a0) | ((uint32)f2bf(a1) << 16);
      ls0 += a0; lq0 += a0 * a0; ls1 += a1; lq1 += a1 * a1;
    }
  }
  if (half == 0) {
    atomicAdd(&ssum[2 * cl], ls0); atomicAdd(&ssum[2 * cl + 1], ls1);
    atomicAdd(&ssq[2 * cl], lq0);  atomicAdd(&ssq[2 * cl + 1], lq1);
  }
  __syncthreads();
  if (tid < 64) {
    int col = chunk * 64 + tid;
    int sp = g & 7;
    atomicAdd(&stat[col * 8 + sp], ssum[tid]);
    atomicAdd(&stat[(DFEAT + col) * 8 + sp], ssq[tid]);
  }
}

// ---------------- gather 2 masked nodes/sample + inline BN6 -> flat f32 -----
__global__ void gather_kernel(const int* __restrict__ mask, const ushort16* __restrict__ R5,
                              const float* __restrict__ stat, const float* __restrict__ g,
                              const float* __restrict__ bb, float invN,
                              float* __restrict__ flat) {
  __shared__ int smin, smax;
  int b = blockIdx.x, t = threadIdx.x;  // 384
  if (t == 0) { smin = 1 << 30; smax = -1; }
  __syncthreads();
  for (int p = t; p < 512; p += 384)
    if (mask[b * 512 + p]) { atomicMin(&smin, p); atomicMax(&smax, p); }
  __syncthreads();
  float s = 0.f, q = 0.f;
  for (int i = 0; i < 8; ++i) { s += stat[t * 8 + i]; q += stat[(DFEAT + t) * 8 + i]; }
  float mean = s * invN, var = q * invN - mean * mean;
  float a = g[t] * rsqrtf(var + 1e-5f), sh = bb[t] - a * mean;
  int sel[2] = {smin, smax};
  for (int j = 0; j < 2; ++j) {
    float v = bf2f(R5[(size_t)(b * 512 + sel[j]) * DFEAT + t]);
    flat[(size_t)b * 768 + j * DFEAT + t] = a * v + sh;
  }
}

// ---------------- tail ------------------------------------------------------
__global__ void cat_gemm_kernel(const float* __restrict__ flat, const float* __restrict__ Wc,
                                const float* __restrict__ bc, float* __restrict__ out) {
  int t = threadIdx.x;
  int j = blockIdx.x * 64 + (t & 63);
  int b = blockIdx.y * 16 + (t >> 6);
  const float* fr = flat + (size_t)b * 768;
  float acc = bc[j];
#pragma unroll 4
  for (int k = 0; k < 768; ++k) acc += fr[k] * Wc[(size_t)k * 768 + j];
  out[(size_t)b * 768 + j] = fmaxf(acc, 0.f);
}
__global__ void bnstats_kernel(const float* __restrict__ catrelu, const float* __restrict__ Hsent,
                               const float* __restrict__ g, const float* __restrict__ bb,
                               float* __restrict__ aff) {
  int c = blockIdx.x * 64 + threadIdx.x;
  float s1 = 0, q1 = 0, s2 = 0, q2 = 0;
  for (int b = 0; b < 64; ++b) {
    float v = catrelu[b * 768 + c]; s1 += v; q1 += v * v;
    float h = Hsent[b * 768 + c];   s2 += h; q2 += h * h;
  }
  const float inv = 1.0f / 64.0f;
  float m1 = s1 * inv, var1 = q1 * inv - m1 * m1;
  float a1 = g[c] * rsqrtf(var1 + 1e-5f);
  aff[c] = a1; aff[768 + c] = bb[c] - a1 * m1;
  float m2 = s2 * inv, var2 = q2 * inv - m2 * m2;
  float a2 = g[768 + c] * rsqrtf(var2 + 1e-5f);
  aff[1536 + c] = a2; aff[2304 + c] = bb[768 + c] - a2 * m2;
}
__global__ void final_kernel(const float* __restrict__ Hs, const float* __restrict__ catrelu,
                             const float* __restrict__ aff, const float* __restrict__ w_out,
                             const float* __restrict__ b_out, float* __restrict__ out) {
  __shared__ float red[12];
  int b = blockIdx.x, t = threadIdx.x;  // 256
  float p0 = 0, p1 = 0, p2 = 0;
  for (int k = t; k < 768; k += 256) {
    float att = (aff[1536 + k] * Hs[b * 768 + k] + aff[2304 + k]) +
                (aff[k] * catrelu[b * 768 + k] + aff[768 + k]);
    p0 += att * w_out[k * 3 + 0];
    p1 += att * w_out[k * 3 + 1];
    p2 += att * w_out[k * 3 + 2];
  }
  for (int off = 32; off > 0; off >>= 1) {
    p0 += __shfl_down(p0, off, 64);
    p1 += __shfl_down(p1, off, 64);
    p2 += __shfl_down(p2, off, 64);
  }
  int wv = t >> 6;
  if ((t & 63) == 0) { red[wv * 3 + 0] = p0; red[wv * 3 + 1] = p1; red[wv * 3 + 2] = p2; }
  __syncthreads();
  if (t == 0) {
    out[b * 3 + 0] = b_out[0] + red[0] + red[3] + red[6] + red[9];
    out[b * 3 + 1] = b_out[1] + red[1] + red[4] + red[7] + red[10];
    out[b * 3 + 2] = b_out[2] + red[2] + red[5] + red[8] + red[11];
  }
}

// ============================================================================
extern "C" void kernel_launch(void* const* d_in, const int* in_sizes, int n_in,
                              void* d_out, int out_size, void* d_ws, size_t ws_size,
                              hipStream_t stream) {
  const float* last_h  = (const float*)d_in[0];
  const float* first_h = (const float*)d_in[1];
  const float* x_nodes = (const float*)d_in[2];
  const int*   edges   = (const int*)d_in[3];
  const int*   mask    = (const int*)d_in[4];
  const float* w_pre1  = (const float*)d_in[5];
  const float* b_pre1  = (const float*)d_in[6];
  const float* w_pre2  = (const float*)d_in[7];
  const float* b_pre2  = (const float*)d_in[8];
  const float* w_conv  = (const float*)d_in[9];
  const float* b_conv  = (const float*)d_in[10];
  const float* bng_g   = (const float*)d_in[11];
  const float* bng_b   = (const float*)d_in[12];
  const float* w_post1 = (const float*)d_in[13];
  const float* b_post1 = (const float*)d_in[14];
  const float* w_post2 = (const float*)d_in[15];
  const float* b_post2 = (const float*)d_in[16];
  const float* w_cat   = (const float*)d_in[17];
  const float* b_cat   = (const float*)d_in[18];
  const float* bn_g    = (const float*)d_in[19];
  const float* bn_b    = (const float*)d_in[20];
  const float* w_out   = (const float*)d_in[21];
  const float* b_out   = (const float*)d_in[22];
  float* out = (float*)d_out;

  const int E = in_sizes[3] / 2;  // 1048576
  const int* e_src = edges;
  const int* e_dst = edges + E;
  const int degB = (E + 255) / 256;

  char* w = (char*)d_ws;
  size_t off = 0;
  auto alloc = [&](size_t bytes) { size_t p = off; off = (off + bytes + 255) & ~(size_t)255; return p; };
  ushort16* buf0   = (ushort16*)(w + alloc((size_t)NNODES * DFEAT * 2));  // A0, R2, RC, R5
  ushort16* buf1   = (ushort16*)(w + alloc((size_t)NNODES * DFEAT * 2));  // R1, XW', R4
  int*    csr      = (int*)(w + alloc((size_t)E * 4));
  int*    rowstart = (int*)(w + alloc((size_t)(NNODES + 1) * 4));
  int*    cursor   = (int*)(w + alloc((size_t)NNODES * 4));
  float*  disq     = (float*)(w + alloc((size_t)NNODES * 4));
  ushort16* BT     = (ushort16*)(w + alloc((size_t)DFEAT * DFEAT * 2));
  float*  biasx    = (float*)(w + alloc(DFEAT * 4));
  float*  flat     = (float*)(w + alloc(64 * 768 * 4));
  float*  catrelu  = (float*)(w + alloc(64 * 768 * 4));
  float*  aff64    = (float*)(w + alloc(4 * 768 * 4));
  float*  Hpart    = (float*)(w + alloc((size_t)64 * 64 * 768 * 4));  // 64 partials
  float*  Hsent    = (float*)(w + alloc(64 * 768 * 4));
  size_t zoff = off;
  int*   degcnt = (int*)(w + alloc((size_t)NNODES * 4));
  float* stats  = (float*)(w + alloc((size_t)5 * 768 * 8 * 4));
  size_t zbytes = off - zoff;

  hipMemsetAsync(w + zoff, 0, zbytes, stream);

  const float invN = 1.0f / (float)NNODES;
  float* st0 = stats + 0 * 768 * 8;
  float* st1 = stats + 1 * 768 * 8;
  float* st2 = stats + 2 * 768 * 8;
  float* st3 = stats + 3 * 768 * 8;
  float* st4 = stats + 4 * 768 * 8;

  // ---- phase A: fused independent prep (vectorized) ----
  prep_kernel<<<4096 + degB + 1024, 256, 0, stream>>>(x_nodes, buf0, e_dst, degcnt, E, degB,
                                                      last_h, first_h, Hpart);
  xform_w_kernel<<<DFEAT, 128, 0, stream>>>(w_pre1, b_pre1, nullptr, nullptr, nullptr, invN, BT, biasx, 300, KPAD1, DFEAT);
  scan_kernel<<<1, 1024, 0, stream>>>(degcnt, rowstart, cursor, disq);
  scatter_kernel<<<degB + 64, 256, 0, stream>>>(e_src, e_dst, cursor, csr, E, degB, Hpart, Hsent);

  dim3 ggrid(NNODES / BM, DFEAT / BN);

  // ---- GEMM1: R1 = relu(x @ W1 + b1), stats->BN0 ----
  gemm_bf16<true, true, false><<<ggrid, 256, 0, stream>>>(buf0, KPAD1, BT, KPAD1, biasx, nullptr, buf1, DFEAT, KPAD1, st0);
  xform_w_kernel<<<DFEAT, 128, 0, stream>>>(w_pre2, b_pre2, st0, bng_g + 0 * DFEAT, bng_b + 0 * DFEAT, invN, BT, biasx, DFEAT, DFEAT, DFEAT);

  // ---- GEMM2: R2 = relu(BN0(R1) @ W2 + b2), stats->BN1 ----
  gemm_bf16<true, true, false><<<ggrid, 256, 0, stream>>>(buf1, DFEAT, BT, DFEAT, biasx, nullptr, buf0, DFEAT, DFEAT, st1);
  xform_w_kernel<<<DFEAT, 128, 0, stream>>>(w_conv + 2 * DFEAT * DFEAT, nullptr, st1, bng_g + 1 * DFEAT, bng_b + 1 * DFEAT, invN, BT, biasx, DFEAT, DFEAT, DFEAT);

  // ---- GEMM3: XW' = disq[row] * (BN1(R2) @ Wc)  (conv i=2 only survives) ----
  gemm_bf16<false, false, true><<<ggrid, 256, 0, stream>>>(buf0, DFEAT, BT, DFEAT, biasx, disq, buf1, DFEAT, DFEAT, nullptr);

  // ---- aggregation (balanced XCD-affine), stats->BN4 ----
  aggregate_kernel<<<6144, 256, 0, stream>>>((const uint32*)buf1, csr, rowstart, disq, b_conv + 2 * DFEAT, (uint32*)buf0, st2);
  xform_w_kernel<<<DFEAT, 128, 0, stream>>>(w_post1, b_post1, st2, bng_g + 4 * DFEAT, bng_b + 4 * DFEAT, invN, BT, biasx, DFEAT, DFEAT, DFEAT);

  // ---- GEMM4: R4 = relu(BN4(RC) @ Wp1 + bp1), stats->BN5 ----
  gemm_bf16<true, true, false><<<ggrid, 256, 0, stream>>>(buf0, DFEAT, BT, DFEAT, biasx, nullptr, buf1, DFEAT, DFEAT, st3);
  xform_w_kernel<<<DFEAT, 128, 0, stream>>>(w_post2, b_post2, st3, bng_g + 5 * DFEAT, bng_b + 5 * DFEAT, invN, BT, biasx, DFEAT, DFEAT, DFEAT);

  // ---- GEMM5: R5 = relu(BN5(R4) @ Wp2 + bp2), stats->BN6 ----
  gemm_bf16<true, true, false><<<ggrid, 256, 0, stream>>>(buf1, DFEAT, BT, DFEAT, biasx, nullptr, buf0, DFEAT, DFEAT, st4);

  // ---- gather (BN6 inline) + tail ----
  gather_kernel<<<64, DFEAT, 0, stream>>>(mask, buf0, st4, bng_g + 6 * DFEAT, bng_b + 6 * DFEAT, invN, flat);
  cat_gemm_kernel<<<dim3(12, 4), 1024, 0, stream>>>(flat, w_cat, b_cat, catrelu);
  bnstats_kernel<<<12, 64, 0, stream>>>(catrelu, Hsent, bn_g, bn_b, aff64);
  final_kernel<<<64, 256, 0, stream>>>(Hsent, catrelu, aff64, w_out, b_out, out);
}

// Round 6
// 859.102 us; speedup vs baseline: 1.0051x; 1.0051x over previous
//
#include <hip/hip_runtime.h>

typedef unsigned int uint32;
typedef unsigned short ushort16;

typedef __attribute__((ext_vector_type(8))) short bf16x8;
typedef __attribute__((ext_vector_type(4))) float f32x4;

#define NNODES 32768
#define DFEAT 384
#define KPAD1 320

__device__ __forceinline__ float bf2f(ushort16 u) {
  union { uint32 i; float f; } x; x.i = ((uint32)u) << 16; return x.f;
}
__device__ __forceinline__ float bflo(uint32 v) {
  union { uint32 i; float f; } x; x.i = v << 16; return x.f;
}
__device__ __forceinline__ float bfhi(uint32 v) {
  union { uint32 i; float f; } x; x.i = v & 0xffff0000u; return x.f;
}
__device__ __forceinline__ ushort16 f2bf(float f) {
  union { float f; uint32 i; } x; x.f = f;
  uint32 r = (x.i + 0x7fffu + ((x.i >> 16) & 1u)) >> 16;
  return (ushort16)r;
}
__device__ __forceinline__ uint32 pack2(float a, float b) {
  return (uint32)f2bf(a) | ((uint32)f2bf(b) << 16);
}

// ---------------- fused prep, ROLE-INTERLEAVED (mod 9) ----------------------
// per 9 blocks: 4x convert_x | 4x deg_count (8-way-spread counters) | 1x sent_mean
// -> atomic-latency blocks co-resident with BW-stream blocks on every CU.
__global__ __launch_bounds__(256) void prep_kernel(
    const float* __restrict__ X, ushort16* __restrict__ A0,
    const int* __restrict__ dst, int* __restrict__ cnt8, int E,
    const float* __restrict__ last, const float* __restrict__ first,
    float* __restrict__ Hpart) {
  __shared__ f32x4 sred[4][192];
  int bx = blockIdx.x;               // grid = 9216 = 1024*9
  int tid = threadIdx.x;
  int role = bx % 9, grp = bx / 9;   // grp in [0,1024)
  if (role < 4) {
    // ---- convert: idx in [0,4096), 8 rows/block, float4 -> packed bf16 ----
    int idx = grp * 4 + role;
    int r = tid >> 5, lane = tid & 31;
    int row = idx * 8 + r;
    const f32x4* xr = (const f32x4*)(X + (size_t)row * 300);  // 75 float4/row
    uint2* ar = (uint2*)(A0 + (size_t)row * KPAD1);           // 80 uint2/row
#pragma unroll
    for (int i = 0; i < 3; ++i) {
      int c = lane + i * 32;
      if (c < 75) {
        f32x4 v = xr[c];
        uint2 o; o.x = pack2(v.x, v.y); o.y = pack2(v.z, v.w);
        ar[c] = o;
      } else if (c < 80) {
        uint2 z; z.x = 0u; z.y = 0u;
        ar[c] = z;
      }
    }
  } else if (role < 8) {
    // ---- deg_count: idx in [0,4096), spread slot = bx&7 ----
    int idx = grp * 4 + (role - 4);
    int e = idx * 256 + tid;
    int sp = bx & 7;
    if (e < E) atomicAdd(&cnt8[(size_t)dst[e] * 8 + sp], 1);
  } else {
    // ---- sent_mean: grp in [0,1024) = b + 64*sc; block-level partial ----
    int b = grp & 63, sc = grp >> 6;
    int w = tid >> 6, lane = tid & 63;
    const f32x4* L = (const f32x4*)last;   // 192 float4 per row
    const f32x4* F = (const f32x4*)first;
    f32x4 a0 = (f32x4)0.f, a1 = (f32x4)0.f, a2 = (f32x4)0.f;
    size_t rowbase = ((size_t)b * 512 + sc * 32 + w) * 192;
#pragma unroll
    for (int i = 0; i < 8; ++i) {
      size_t rb = rowbase + (size_t)(4 * 192) * i;
      f32x4 l0 = L[rb + lane],       f0 = F[rb + lane];
      f32x4 l1 = L[rb + lane + 64],  f1 = F[rb + lane + 64];
      f32x4 l2 = L[rb + lane + 128], f2 = F[rb + lane + 128];
      a0 += l0 + f0; a1 += l1 + f1; a2 += l2 + f2;
    }
    sred[w][lane] = a0; sred[w][lane + 64] = a1; sred[w][lane + 128] = a2;
    __syncthreads();
    if (tid < 192) {
      f32x4 h = sred[0][tid] + sred[1][tid] + sred[2][tid] + sred[3][tid];
      ((f32x4*)Hpart)[((size_t)sc * 64 + b) * 192 + tid] = h;
    }
  }
}

// ---------------- scan (+ disq folded), 8-slot fold, int4 reads -------------
__global__ void scan_kernel(const int* __restrict__ cnt8, int* __restrict__ row_start,
                            int* __restrict__ cursor, float* __restrict__ disq) {
  __shared__ int buf[1024];
  int t = threadIdx.x;
  int base = t * 32;
  const int4* c4 = (const int4*)cnt8;   // node j -> c4[2j], c4[2j+1]
  int deg[32];
  int s = 0;
#pragma unroll
  for (int i = 0; i < 32; ++i) {
    int4 a = c4[(size_t)(base + i) * 2];
    int4 b = c4[(size_t)(base + i) * 2 + 1];
    int d = a.x + a.y + a.z + a.w + b.x + b.y + b.z + b.w;
    deg[i] = d; s += d;
  }
  buf[t] = s; __syncthreads();
  int x = s;
  for (int off = 1; off < 1024; off <<= 1) {
    int v = (t >= off) ? buf[t - off] : 0;
    __syncthreads();
    x += v; buf[t] = x;
    __syncthreads();
  }
  int run = x - s;
#pragma unroll
  for (int i = 0; i < 32; ++i) {
    int j = base + i;
    row_start[j] = run; cursor[j] = run;
    disq[j] = rsqrtf((float)deg[i] + 1.0f);  // +1 self loop
    run += deg[i];
  }
  if (t == 1023) row_start[NNODES] = run;
}

// ---------------- scatter (+ hsent fold, float4, 16 partials) ---------------
__global__ __launch_bounds__(256) void scatter_kernel(
    const int* __restrict__ src, const int* __restrict__ dst,
    int* __restrict__ cursor, int* __restrict__ csr, int E, int degB,
    const float* __restrict__ Hpart, float* __restrict__ Hsent) {
  int bx = blockIdx.x, t = threadIdx.x;
  if (bx < degB) {
    int e = bx * 256 + t;
    if (e < E) {
      int d = dst[e];
      int pos = atomicAdd(&cursor[d], 1);
      csr[pos] = src[e];
    }
  } else {
    int b = bx - degB;                 // [0,64)
    if (t < 192) {
      const f32x4* HP = (const f32x4*)Hpart;
      f32x4 h = (f32x4)0.f;
#pragma unroll
      for (int p = 0; p < 16; ++p)
        h += HP[((size_t)p * 64 + b) * 192 + t];
      ((f32x4*)Hsent)[(size_t)b * 192 + t] = h * (0.5f / 512.f);
    }
  }
}

// ---------------- weight transform with inline BN-affine from spread stats --
__global__ void xform_w_kernel(const float* __restrict__ W, const float* __restrict__ bias,
                               const float* __restrict__ stat, const float* __restrict__ g,
                               const float* __restrict__ bb, float invN,
                               ushort16* __restrict__ BT, float* __restrict__ bias_out,
                               int K, int Kpad, int Nw) {
  __shared__ float red[128];
  int n = blockIdx.x, t = threadIdx.x;
  float part = 0.f;
  for (int k = t; k < Kpad; k += 128) {
    ushort16 o = 0; float contrib = 0.f;
    if (k < K) {
      float ak = 1.f, shk = 0.f;
      if (stat) {
        float s = 0.f, q = 0.f;
        for (int i = 0; i < 8; ++i) { s += stat[k * 8 + i]; q += stat[(DFEAT + k) * 8 + i]; }
        float mean = s * invN, var = q * invN - mean * mean;
        ak = g[k] * rsqrtf(var + 1e-5f);
        shk = bb[k] - ak * mean;
      }
      float w = W[(size_t)k * Nw + n];
      o = f2bf(ak * w);
      contrib = shk * w;
    }
    BT[(size_t)n * Kpad + k] = o;
    part += contrib;
  }
  red[t] = part; __syncthreads();
  for (int off = 64; off > 0; off >>= 1) {
    if (t < off) red[t] += red[t + off];
    __syncthreads();
  }
  if (t == 0) bias_out[n] = (bias ? bias[n] : 0.f) + red[0];
}

// ---------------- MFMA bf16 GEMM with fused stats / row-scale ---------------
#define BM 128
#define BN 128
#define BKT 32
#define LDT 40  // BKT + 8 pad shorts

template <bool RELU, bool STATS, bool RSCALE>
__global__ __launch_bounds__(256) void gemm_bf16(
    const ushort16* __restrict__ A, int lda, const ushort16* __restrict__ BT, int ldb,
    const float* __restrict__ bias, const float* __restrict__ rowscale,
    ushort16* __restrict__ C, int Ntot, int K, float* __restrict__ stat) {
  __shared__ __attribute__((aligned(16))) ushort16 As[BM * LDT];
  __shared__ __attribute__((aligned(16))) ushort16 Bs[BN * LDT];
  __shared__ float ssum[BN], ssq[BN];
  int bm0 = blockIdx.x * BM, bn0 = blockIdx.y * BN;
  int tid = threadIdx.x;
  if (STATS) {
    if (tid < BN) { ssum[tid] = 0.f; ssq[tid] = 0.f; }
  }
  int lane = tid & 63, wave = tid >> 6;
  int wm = (wave & 1) * 64, wn = (wave >> 1) * 64;
  int l15 = lane & 15, quad = lane >> 4;

  f32x4 acc[4][4];
  for (int i = 0; i < 4; ++i)
    for (int j = 0; j < 4; ++j) acc[i][j] = (f32x4)0.f;

  for (int kk = 0; kk < K; kk += BKT) {
    __syncthreads();
    for (int i = 0; i < 2; ++i) {
      int chunk = tid + i * 256;
      int row = chunk >> 2, cc = chunk & 3;
      uint4 va = *(const uint4*)(A + (size_t)(bm0 + row) * lda + kk + cc * 8);
      *(uint4*)(&As[row * LDT + cc * 8]) = va;
      uint4 vb = *(const uint4*)(BT + (size_t)(bn0 + row) * ldb + kk + cc * 8);
      *(uint4*)(&Bs[row * LDT + cc * 8]) = vb;
    }
    __syncthreads();
    bf16x8 af[4], bfr[4];
    for (int mi = 0; mi < 4; ++mi)
      af[mi] = *(const bf16x8*)(&As[(wm + mi * 16 + l15) * LDT + quad * 8]);
    for (int ni = 0; ni < 4; ++ni)
      bfr[ni] = *(const bf16x8*)(&Bs[(wn + ni * 16 + l15) * LDT + quad * 8]);
    for (int mi = 0; mi < 4; ++mi)
      for (int ni = 0; ni < 4; ++ni)
        acc[mi][ni] = __builtin_amdgcn_mfma_f32_16x16x32_bf16(af[mi], bfr[ni], acc[mi][ni], 0, 0, 0);
  }
  for (int ni = 0; ni < 4; ++ni) {
    int coll = wn + ni * 16 + l15;
    int col = bn0 + coll;
    float bv = bias[col];
    float s = 0.f, q = 0.f;
    for (int mi = 0; mi < 4; ++mi) {
      for (int r = 0; r < 4; ++r) {
        int row = bm0 + wm + mi * 16 + quad * 4 + r;
        float v = acc[mi][ni][r] + bv;
        if (RELU) v = fmaxf(v, 0.f);
        if (RSCALE) v *= rowscale[row];
        C[(size_t)row * Ntot + col] = f2bf(v);
        if (STATS) { s += v; q += v * v; }
      }
    }
    if (STATS) { atomicAdd(&ssum[coll], s); atomicAdd(&ssq[coll], q); }
  }
  if (STATS) {
    __syncthreads();
    int sp = blockIdx.x & 7;
    if (tid < BN) {
      atomicAdd(&stat[(bn0 + tid) * 8 + sp], ssum[tid]);
      atomicAdd(&stat[(DFEAT + bn0 + tid) * 8 + sp], ssq[tid]);
    }
  }
}

// ---------------- balanced XCD-affine GCN aggregation -----------------------
// Proven r1 inner loop (32-lane uint32 gather) + balanced unit mapping:
// 6 chunks x 1024 groups = 6144 units; XCD k (bx&7) owns units [768k,768k+768)
__global__ void __launch_bounds__(256) aggregate_kernel(
    const uint32* __restrict__ XWs, const int* __restrict__ csr,
    const int* __restrict__ row_start, const float* __restrict__ disq,
    const float* __restrict__ bconv, uint32* __restrict__ RC2,
    float* __restrict__ stat) {
  int bx = blockIdx.x;                 // grid 6144
  int unit = (bx & 7) * 768 + (bx >> 3);
  int chunk = unit >> 10;              // [0,6)
  int g = unit & 1023;                 // [0,1024)
  __shared__ float ssum[64], ssq[64];
  int tid = threadIdx.x;
  if (tid < 64) { ssum[tid] = 0.f; ssq[tid] = 0.f; }
  __syncthreads();
  int lane = tid & 63, wave = tid >> 6;
  int half = lane >> 5, cl = lane & 31;
  int hb = half << 5;
  int cbase = chunk * 32;
  float b0 = bconv[chunk * 64 + 2 * cl], b1 = bconv[chunk * 64 + 2 * cl + 1];
  float ls0 = 0.f, ls1 = 0.f, lq0 = 0.f, lq1 = 0.f;
  int nodebase = (g * 4 + wave) * 8;
  for (int ni = 0; ni < 8; ++ni) {
    int n = nodebase + ni;
    int beg = row_start[n], end = row_start[n + 1];
    int deg = end - beg;
    int len0 = (deg + 1) >> 1;  // half 0 gets the longer part
    int myBeg = beg + (half ? len0 : 0);
    int myLen = half ? (deg - len0) : len0;
    float a0, a1;
    if (half == 0) {
      uint32 v = XWs[(size_t)n * 192 + cbase + cl];
      a0 = bflo(v); a1 = bfhi(v);
    } else { a0 = 0.f; a1 = 0.f; }
    for (int bb0 = 0; bb0 < len0; bb0 += 32) {
      int rem = myLen - bb0;
      int idx = (cl < rem) ? csr[myBeg + bb0 + cl] : -1;
      int jmax = min(32, len0 - bb0);  // uniform over wave
      int j = 0;
      for (; j + 8 <= jmax; j += 8) {
        uint32 v[8];
#pragma unroll
        for (int jj = 0; jj < 8; ++jj) {
          int s = __shfl(idx, hb + j + jj, 64);
          int sa = (s < 0) ? 0 : s;                 // safe address
          uint32 m = (s < 0) ? 0u : 0xffffffffu;    // zero-mask invalid
          v[jj] = XWs[(size_t)sa * 192 + cbase + cl] & m;
        }
#pragma unroll
        for (int jj = 0; jj < 8; ++jj) { a0 += bflo(v[jj]); a1 += bfhi(v[jj]); }
      }
      for (; j < jmax; ++j) {
        int s = __shfl(idx, hb + j, 64);
        int sa = (s < 0) ? 0 : s;
        uint32 m = (s < 0) ? 0u : 0xffffffffu;
        uint32 v = XWs[(size_t)sa * 192 + cbase + cl] & m;
        a0 += bflo(v); a1 += bfhi(v);
      }
    }
    a0 += __shfl_xor(a0, 32, 64);
    a1 += __shfl_xor(a1, 32, 64);
    if (half == 0) {
      float din = disq[n];
      a0 = fmaxf(din * a0 + b0, 0.f);
      a1 = fmaxf(din * a1 + b1, 0.f);
      RC2[(size_t)n * 192 + cbase + cl] = (uint32)f2bf(a0) | ((uint32)f2bf(a1) << 16);
      ls0 += a0; lq0 += a0 * a0; ls1 += a1; lq1 += a1 * a1;
    }
  }
  if (half == 0) {
    atomicAdd(&ssum[2 * cl], ls0); atomicAdd(&ssum[2 * cl + 1], ls1);
    atomicAdd(&ssq[2 * cl], lq0);  atomicAdd(&ssq[2 * cl + 1], lq1);
  }
  __syncthreads();
  if (tid < 64) {
    int col = chunk * 64 + tid;
    int sp = g & 7;
    atomicAdd(&stat[col * 8 + sp], ssum[tid]);
    atomicAdd(&stat[(DFEAT + col) * 8 + sp], ssq[tid]);
  }
}

// ---------------- gather 2 masked nodes/sample + inline BN6 -> flat f32 -----
__global__ void gather_kernel(const int* __restrict__ mask, const ushort16* __restrict__ R5,
                              const float* __restrict__ stat, const float* __restrict__ g,
                              const float* __restrict__ bb, float invN,
                              float* __restrict__ flat) {
  __shared__ int smin, smax;
  int b = blockIdx.x, t = threadIdx.x;  // 384
  if (t == 0) { smin = 1 << 30; smax = -1; }
  __syncthreads();
  for (int p = t; p < 512; p += 384)
    if (mask[b * 512 + p]) { atomicMin(&smin, p); atomicMax(&smax, p); }
  __syncthreads();
  float s = 0.f, q = 0.f;
  for (int i = 0; i < 8; ++i) { s += stat[t * 8 + i]; q += stat[(DFEAT + t) * 8 + i]; }
  float mean = s * invN, var = q * invN - mean * mean;
  float a = g[t] * rsqrtf(var + 1e-5f), sh = bb[t] - a * mean;
  int sel[2] = {smin, smax};
  for (int j = 0; j < 2; ++j) {
    float v = bf2f(R5[(size_t)(b * 512 + sel[j]) * DFEAT + t]);
    flat[(size_t)b * 768 + j * DFEAT + t] = a * v + sh;
  }
}

// ---------------- tail ------------------------------------------------------
__global__ void cat_gemm_kernel(const float* __restrict__ flat, const float* __restrict__ Wc,
                                const float* __restrict__ bc, float* __restrict__ out) {
  int t = threadIdx.x;
  int j = blockIdx.x * 64 + (t & 63);
  int b = blockIdx.y * 16 + (t >> 6);
  const float* fr = flat + (size_t)b * 768;
  float acc = bc[j];
#pragma unroll 4
  for (int k = 0; k < 768; ++k) acc += fr[k] * Wc[(size_t)k * 768 + j];
  out[(size_t)b * 768 + j] = fmaxf(acc, 0.f);
}
__global__ void bnstats_kernel(const float* __restrict__ catrelu, const float* __restrict__ Hsent,
                               const float* __restrict__ g, const float* __restrict__ bb,
                               float* __restrict__ aff) {
  int c = blockIdx.x * 64 + threadIdx.x;
  float s1 = 0, q1 = 0, s2 = 0, q2 = 0;
  for (int b = 0; b < 64; ++b) {
    float v = catrelu[b * 768 + c]; s1 += v; q1 += v * v;
    float h = Hsent[b * 768 + c];   s2 += h; q2 += h * h;
  }
  const float inv = 1.0f / 64.0f;
  float m1 = s1 * inv, var1 = q1 * inv - m1 * m1;
  float a1 = g[c] * rsqrtf(var1 + 1e-5f);
  aff[c] = a1; aff[768 + c] = bb[c] - a1 * m1;
  float m2 = s2 * inv, var2 = q2 * inv - m2 * m2;
  float a2 = g[768 + c] * rsqrtf(var2 + 1e-5f);
  aff[1536 + c] = a2; aff[2304 + c] = bb[768 + c] - a2 * m2;
}
__global__ void final_kernel(const float* __restrict__ Hs, const float* __restrict__ catrelu,
                             const float* __restrict__ aff, const float* __restrict__ w_out,
                             const float* __restrict__ b_out, float* __restrict__ out) {
  __shared__ float red[12];
  int b = blockIdx.x, t = threadIdx.x;  // 256
  float p0 = 0, p1 = 0, p2 = 0;
  for (int k = t; k < 768; k += 256) {
    float att = (aff[1536 + k] * Hs[b * 768 + k] + aff[2304 + k]) +
                (aff[k] * catrelu[b * 768 + k] + aff[768 + k]);
    p0 += att * w_out[k * 3 + 0];
    p1 += att * w_out[k * 3 + 1];
    p2 += att * w_out[k * 3 + 2];
  }
  for (int off = 32; off > 0; off >>= 1) {
    p0 += __shfl_down(p0, off, 64);
    p1 += __shfl_down(p1, off, 64);
    p2 += __shfl_down(p2, off, 64);
  }
  int wv = t >> 6;
  if ((t & 63) == 0) { red[wv * 3 + 0] = p0; red[wv * 3 + 1] = p1; red[wv * 3 + 2] = p2; }
  __syncthreads();
  if (t == 0) {
    out[b * 3 + 0] = b_out[0] + red[0] + red[3] + red[6] + red[9];
    out[b * 3 + 1] = b_out[1] + red[1] + red[4] + red[7] + red[10];
    out[b * 3 + 2] = b_out[2] + red[2] + red[5] + red[8] + red[11];
  }
}

// ============================================================================
extern "C" void kernel_launch(void* const* d_in, const int* in_sizes, int n_in,
                              void* d_out, int out_size, void* d_ws, size_t ws_size,
                              hipStream_t stream) {
  const float* last_h  = (const float*)d_in[0];
  const float* first_h = (const float*)d_in[1];
  const float* x_nodes = (const float*)d_in[2];
  const int*   edges   = (const int*)d_in[3];
  const int*   mask    = (const int*)d_in[4];
  const float* w_pre1  = (const float*)d_in[5];
  const float* b_pre1  = (const float*)d_in[6];
  const float* w_pre2  = (const float*)d_in[7];
  const float* b_pre2  = (const float*)d_in[8];
  const float* w_conv  = (const float*)d_in[9];
  const float* b_conv  = (const float*)d_in[10];
  const float* bng_g   = (const float*)d_in[11];
  const float* bng_b   = (const float*)d_in[12];
  const float* w_post1 = (const float*)d_in[13];
  const float* b_post1 = (const float*)d_in[14];
  const float* w_post2 = (const float*)d_in[15];
  const float* b_post2 = (const float*)d_in[16];
  const float* w_cat   = (const float*)d_in[17];
  const float* b_cat   = (const float*)d_in[18];
  const float* bn_g    = (const float*)d_in[19];
  const float* bn_b    = (const float*)d_in[20];
  const float* w_out   = (const float*)d_in[21];
  const float* b_out   = (const float*)d_in[22];
  float* out = (float*)d_out;

  const int E = in_sizes[3] / 2;  // 1048576
  const int* e_src = edges;
  const int* e_dst = edges + E;
  const int degB = (E + 255) / 256;  // 4096

  char* w = (char*)d_ws;
  size_t off = 0;
  auto alloc = [&](size_t bytes) { size_t p = off; off = (off + bytes + 255) & ~(size_t)255; return p; };
  ushort16* buf0   = (ushort16*)(w + alloc((size_t)NNODES * DFEAT * 2));  // A0, R2, RC, R5
  ushort16* buf1   = (ushort16*)(w + alloc((size_t)NNODES * DFEAT * 2));  // R1, XW', R4
  int*    csr      = (int*)(w + alloc((size_t)E * 4));
  int*    rowstart = (int*)(w + alloc((size_t)(NNODES + 1) * 4));
  int*    cursor   = (int*)(w + alloc((size_t)NNODES * 4));
  float*  disq     = (float*)(w + alloc((size_t)NNODES * 4));
  ushort16* BT     = (ushort16*)(w + alloc((size_t)DFEAT * DFEAT * 2));
  float*  biasx    = (float*)(w + alloc(DFEAT * 4));
  float*  flat     = (float*)(w + alloc(64 * 768 * 4));
  float*  catrelu  = (float*)(w + alloc(64 * 768 * 4));
  float*  aff64    = (float*)(w + alloc(4 * 768 * 4));
  float*  Hpart    = (float*)(w + alloc((size_t)16 * 64 * 768 * 4));  // 16 partials
  float*  Hsent    = (float*)(w + alloc(64 * 768 * 4));
  size_t zoff = off;
  int*   degcnt8 = (int*)(w + alloc((size_t)NNODES * 8 * 4));  // 8-way spread
  float* stats   = (float*)(w + alloc((size_t)5 * 768 * 8 * 4));
  size_t zbytes = off - zoff;

  hipMemsetAsync(w + zoff, 0, zbytes, stream);

  const float invN = 1.0f / (float)NNODES;
  float* st0 = stats + 0 * 768 * 8;
  float* st1 = stats + 1 * 768 * 8;
  float* st2 = stats + 2 * 768 * 8;
  float* st3 = stats + 3 * 768 * 8;
  float* st4 = stats + 4 * 768 * 8;

  // ---- phase A: fused role-interleaved prep ----
  prep_kernel<<<9216, 256, 0, stream>>>(x_nodes, buf0, e_dst, degcnt8, E,
                                        last_h, first_h, Hpart);
  xform_w_kernel<<<DFEAT, 128, 0, stream>>>(w_pre1, b_pre1, nullptr, nullptr, nullptr, invN, BT, biasx, 300, KPAD1, DFEAT);
  scan_kernel<<<1, 1024, 0, stream>>>(degcnt8, rowstart, cursor, disq);
  scatter_kernel<<<degB + 64, 256, 0, stream>>>(e_src, e_dst, cursor, csr, E, degB, Hpart, Hsent);

  dim3 ggrid(NNODES / BM, DFEAT / BN);

  // ---- GEMM1: R1 = relu(x @ W1 + b1), stats->BN0 ----
  gemm_bf16<true, true, false><<<ggrid, 256, 0, stream>>>(buf0, KPAD1, BT, KPAD1, biasx, nullptr, buf1, DFEAT, KPAD1, st0);
  xform_w_kernel<<<DFEAT, 128, 0, stream>>>(w_pre2, b_pre2, st0, bng_g + 0 * DFEAT, bng_b + 0 * DFEAT, invN, BT, biasx, DFEAT, DFEAT, DFEAT);

  // ---- GEMM2: R2 = relu(BN0(R1) @ W2 + b2), stats->BN1 ----
  gemm_bf16<true, true, false><<<ggrid, 256, 0, stream>>>(buf1, DFEAT, BT, DFEAT, biasx, nullptr, buf0, DFEAT, DFEAT, st1);
  xform_w_kernel<<<DFEAT, 128, 0, stream>>>(w_conv + 2 * DFEAT * DFEAT, nullptr, st1, bng_g + 1 * DFEAT, bng_b + 1 * DFEAT, invN, BT, biasx, DFEAT, DFEAT, DFEAT);

  // ---- GEMM3: XW' = disq[row] * (BN1(R2) @ Wc)  (conv i=2 only survives) ----
  gemm_bf16<false, false, true><<<ggrid, 256, 0, stream>>>(buf0, DFEAT, BT, DFEAT, biasx, disq, buf1, DFEAT, DFEAT, nullptr);

  // ---- aggregation (balanced XCD-affine), stats->BN4 ----
  aggregate_kernel<<<6144, 256, 0, stream>>>((const uint32*)buf1, csr, rowstart, disq, b_conv + 2 * DFEAT, (uint32*)buf0, st2);
  xform_w_kernel<<<DFEAT, 128, 0, stream>>>(w_post1, b_post1, st2, bng_g + 4 * DFEAT, bng_b + 4 * DFEAT, invN, BT, biasx, DFEAT, DFEAT, DFEAT);

  // ---- GEMM4: R4 = relu(BN4(RC) @ Wp1 + bp1), stats->BN5 ----
  gemm_bf16<true, true, false><<<ggrid, 256, 0, stream>>>(buf0, DFEAT, BT, DFEAT, biasx, nullptr, buf1, DFEAT, DFEAT, st3);
  xform_w_kernel<<<DFEAT, 128, 0, stream>>>(w_post2, b_post2, st3, bng_g + 5 * DFEAT, bng_b + 5 * DFEAT, invN, BT, biasx, DFEAT, DFEAT, DFEAT);

  // ---- GEMM5: R5 = relu(BN5(R4) @ Wp2 + bp2), stats->BN6 ----
  gemm_bf16<true, true, false><<<ggrid, 256, 0, stream>>>(buf1, DFEAT, BT, DFEAT, biasx, nullptr, buf0, DFEAT, DFEAT, st4);

  // ---- gather (BN6 inline) + tail ----
  gather_kernel<<<64, DFEAT, 0, stream>>>(mask, buf0, st4, bng_g + 6 * DFEAT, bng_b + 6 * DFEAT, invN, flat);
  cat_gemm_kernel<<<dim3(12, 4), 1024, 0, stream>>>(flat, w_cat, b_cat, catrelu);
  bnstats_kernel<<<12, 64, 0, stream>>>(catrelu, Hsent, bn_g, bn_b, aff64);
  final_kernel<<<64, 256, 0, stream>>>(Hsent, catrelu, aff64, w_out, b_out, out);
}